// Round 7
// baseline (627.229 us; speedup 1.0000x reference)
//
#include <hip/hip_runtime.h>

#define NN 100000   // nodes
#define NE 640000   // edges
#define RR 8        // relations
#define NT 3125     // 32-node tiles (NN/32)
#define CAP 512     // per-tile edge capacity (Poisson mean 205, +21 sigma)
// D = HID = OUT = 128 hard-coded below.

typedef unsigned short u16;
typedef u16 u16x4 __attribute__((ext_vector_type(4)));
typedef u16 u16x8 __attribute__((ext_vector_type(8)));
typedef __bf16 bf16x8 __attribute__((ext_vector_type(8)));
typedef float f32x4 __attribute__((ext_vector_type(4)));

// ---- workspace layout (bytes) ----
#define OFF_XB      0u          // bf16 N*128            = 25,600,000
#define OFF_WT      25600000u   // bf16 [9][128o][128d]  = 294,912 (8 rels + loop_w)
#define OFF_W1T     25894912u   // bf16 [256o][256i]     = 131,072
#define OFF_W2T     26025984u   // bf16 [128o][384i]     = 98,304
#define OFF_BUCKET  26124288u   // uint NT*CAP (packed src|rel<<17|dstlo<<20) = 6,400,000
#define OFF_CUR     32524288u   // int NT = 12,500
#define OFF_MSGB    32536800u   // bf16 N*128 = 25,600,000 (16B aligned)

__device__ inline u16 f2bf(float f) {
  unsigned u = __float_as_uint(f);
  u += 0x7FFF + ((u >> 16) & 1);   // round-to-nearest-even
  return (u16)(u >> 16);
}
__device__ inline float bf2f(u16 h) { return __uint_as_float(((unsigned)h) << 16); }

// ---------------- prep: dtype cvt (x, W_rel+loop, W1, W2) + tile scatter ---
// grid: [0,12500) x | [12500,13076) wrel | [13076,13332) w1 |
//       [13332,13524) w2 | [13524,16024) edge scatter (640K edges)
__global__ void k_cvt_all(const float* __restrict__ x,
                          const float* __restrict__ W, const float* __restrict__ Lw,
                          const float* __restrict__ W1, const float* __restrict__ W2,
                          const int* __restrict__ src, const int* __restrict__ dst,
                          const int* __restrict__ et,
                          u16* __restrict__ xb, u16* __restrict__ Wt,
                          u16* __restrict__ W1t, u16* __restrict__ W2t,
                          int* __restrict__ cur, unsigned* __restrict__ bucket) {
  const int b = blockIdx.x, tid = threadIdx.x;
  if (b < 12500) {
    const int i = (b * 256 + tid) * 4;
    const float4 v = *(const float4*)(x + i);
    u16x4 o;
    o.x = f2bf(v.x); o.y = f2bf(v.y); o.z = f2bf(v.z); o.w = f2bf(v.w);
    *(u16x4*)(xb + i) = o;
  } else if (b < 13076) {          // 9*16384 = 147456 elems
    const int idx = (b - 12500) * 256 + tid;
    const int r = idx >> 14, o = (idx >> 7) & 127, d = idx & 127;
    Wt[idx] = f2bf(r < 8 ? W[(r << 14) + (d << 7) + o] : Lw[(d << 7) + o]);
  } else if (b < 13332) {          // 65536 elems
    const int idx = (b - 13076) * 256 + tid;
    const int o = idx >> 8, i = idx & 255;
    W1t[idx] = f2bf(W1[i * 256 + o]);
  } else if (b < 13524) {          // 49152 elems
    const int idx = (b - 13332) * 256 + tid;
    const int o = idx / 384, i = idx % 384;
    W2t[idx] = f2bf(W2[i * 128 + o]);
  } else {                         // edge scatter: append to per-tile bucket
    const int e = (b - 13524) * 256 + tid;   // grid sized exactly to NE
    const int d = dst[e], r = et[e];
    const int t = d >> 5;
    const int pos = atomicAdd(&cur[t], 1);
    if (pos < CAP)
      bucket[t * CAP + pos] =
          (unsigned)src[e] | ((unsigned)r << 17) | ((unsigned)(d & 31) << 20);
  }
}

// ---------------- k_msg: per-32-node tile edge aggregate ------------------
// In-LDS counting sort (proven r6) + self-loop + 8 phases x 1 relation-tile
// (proven r4 structure) -> msg bf16 to global.  LDS ~16KB -> 8 blocks/CU.
#define ATS 136    // A-tile row stride (u16): 68 words, %32=4 -> 2-way (free)
__global__ __launch_bounds__(256, 8) void k_msg(
    const u16* __restrict__ xb, const u16* __restrict__ Wt,
    const int* __restrict__ cur, const unsigned* __restrict__ bucket,
    const float* __restrict__ rel_bias, u16* __restrict__ msgb) {
  __shared__ u16 At[32 * ATS];        // 8,704 B
  __shared__ unsigned wlds[CAP];      // 2,048 B (sorted edge words)
  __shared__ unsigned wraw[CAP];      // 2,048 B
  __shared__ int scnt[256];           // 1,024 B
  __shared__ int spos[256];           // 1,024 B
  __shared__ int coff[257];           // 1,028 B
  const int tid = threadIdx.x;
  const int tile = blockIdx.x;
  const int v0 = tile * 32;
  const int wave = tid >> 6, lane = tid & 63;
  const int l16 = lane & 15, quad = lane >> 4;
  const int rt = wave & 1, cb = (wave >> 1) << 6;
  const int grp = tid >> 4, l16g = tid & 15;   // gather: 16 lanes per node

  // ---- in-LDS counting sort by (node,rel) bin ----
  const int n_raw = cur[tile];
  const int n = n_raw < CAP ? n_raw : CAP;
  for (int i = tid; i < n; i += 256) wraw[i] = bucket[tile * CAP + i];
  scnt[tid] = 0;
  __syncthreads();
  for (int i = tid; i < n; i += 256)
    atomicAdd(&scnt[(wraw[i] >> 17) & 0xFF], 1);   // bin = dstlo*8 + rel
  __syncthreads();
  const int myc = scnt[tid];
  for (int d = 1; d < 256; d <<= 1) {               // Hillis-Steele inclusive
    const int t = (tid >= d) ? scnt[tid - d] : 0;
    __syncthreads();
    scnt[tid] += t;
    __syncthreads();
  }
  coff[tid] = scnt[tid] - myc;                      // exclusive
  spos[tid] = scnt[tid] - myc;
  if (tid == 0) coff[256] = n;
  __syncthreads();
  for (int i = tid; i < n; i += 256) {
    const unsigned w = wraw[i];
    const int pos = atomicAdd(&spos[(w >> 17) & 0xFF], 1);
    wlds[pos] = w;
  }

  f32x4 acc[4] = {};

  // ---- self-loop: A-frags straight from global xb ----
  {
    const u16* xp = xb + ((size_t)(v0 + rt * 16 + l16) << 7) + quad * 8;
    bf16x8 afr[4];
#pragma unroll
    for (int t = 0; t < 4; ++t) afr[t] = *(const bf16x8*)(xp + t * 32);
    const u16* wb = Wt + (8 << 14);
#pragma unroll
    for (int c = 0; c < 4; ++c) {
      const u16* wp = wb + (size_t)(cb + c * 16 + l16) * 128 + quad * 8;
#pragma unroll
      for (int t = 0; t < 4; ++t)
        acc[c] = __builtin_amdgcn_mfma_f32_16x16x32_bf16(afr[t], *(const bf16x8*)(wp + t * 32), acc[c], 0, 0, 0);
    }
  }
  __syncthreads();

  for (int ph = 0; ph < 8; ++ph) {
    // ---- gather+accumulate: 2 independent node streams per 16-lane group --
    {
      const int nodeA = grp, nodeB = grp + 16;
      const int begA = coff[nodeA * 8 + ph];
      const int nA   = coff[nodeA * 8 + ph + 1] - begA;
      const int begB = coff[nodeB * 8 + ph];
      const int nB   = coff[nodeB * 8 + ph + 1] - begB;
      float a0[8] = {}, a1[8] = {};
      const int nmax = nA > nB ? nA : nB;
      for (int j = 0; j < nmax; ++j) {
        const bool dA = j < nA, dB = j < nB;
        unsigned wA = 0, wB = 0;
        if (dA) wA = wlds[begA + j];
        if (dB) wB = wlds[begB + j];
        u16x8 hA, hB;
        if (dA) hA = *(const u16x8*)(xb + ((size_t)(wA & 0x1FFFFu) << 7) + l16g * 8);
        if (dB) hB = *(const u16x8*)(xb + ((size_t)(wB & 0x1FFFFu) << 7) + l16g * 8);
        if (dA) {
#pragma unroll
          for (int u = 0; u < 8; ++u) a0[u] += bf2f(hA[u]);
        }
        if (dB) {
#pragma unroll
          for (int u = 0; u < 8; ++u) a1[u] += bf2f(hB[u]);
        }
      }
      u16x8 o0, o1;
#pragma unroll
      for (int u = 0; u < 8; ++u) { o0[u] = f2bf(a0[u]); o1[u] = f2bf(a1[u]); }
      *(u16x8*)&At[nodeA * ATS + l16g * 8] = o0;
      *(u16x8*)&At[nodeB * ATS + l16g * 8] = o1;
    }
    __syncthreads();

    // ---- MFMA over this relation's tile ----
    {
      bf16x8 afr[4];
#pragma unroll
      for (int t = 0; t < 4; ++t)
        afr[t] = *(const bf16x8*)&At[(rt * 16 + l16) * ATS + quad * 8 + t * 32];
      const u16* wb = Wt + (ph << 14);
#pragma unroll
      for (int c = 0; c < 4; ++c) {
        const u16* wp = wb + (size_t)(cb + c * 16 + l16) * 128 + quad * 8;
#pragma unroll
        for (int t = 0; t < 4; ++t)
          acc[c] = __builtin_amdgcn_mfma_f32_16x16x32_bf16(afr[t], *(const bf16x8*)(wp + t * 32), acc[c], 0, 0, 0);
      }
    }
    __syncthreads();
  }

  // ---- epilogue: msg = acc + rel_bias -> global bf16 ----
#pragma unroll
  for (int c = 0; c < 4; ++c) {
    const int col = cb + c * 16 + l16;
    const float bias = rel_bias[col];
#pragma unroll
    for (int reg = 0; reg < 4; ++reg) {
      const int row = v0 + rt * 16 + quad * 4 + reg;
      msgb[(size_t)row * 128 + col] = f2bf(acc[c][reg] + bias);
    }
  }
}

// ---------------- k_mlp: B+C with LDS-staged weight slices ----------------
// mid = tanh([x | msg] @ W1 + b1); out = [x | mid] @ W2 + b2.
// Per kt, the k-slice of W1t/W2t is staged cooperatively into LDS once
// (coalesced 64B/lane) and all 4 waves' MFMA B-frags read LDS -- kills the
// per-lane scattered global W loads that made B/C latency-bound (~180 us).
// LDS 52.2 KB -> 3 blocks/CU: one block's stage hides under another's MFMA.
#define A1S 264   // A1/Ht row stride (u16)
#define WSS 36    // W-slice row stride (u16): 72B, 8B-aligned (b64 reads)
__global__ __launch_bounds__(256, 3) void k_mlp(
    const u16* __restrict__ xb, const u16* __restrict__ msgb,
    const u16* __restrict__ W1t, const float* __restrict__ b1,
    const u16* __restrict__ W2t, const float* __restrict__ b2,
    float* __restrict__ out) {
  __shared__ u16 A1[32 * A1S];    // 16,896 B: cols 0-127 x, 128-255 msg
  __shared__ u16 Ht[32 * A1S];    // 16,896 B: mid (256 cols used)
  __shared__ u16 Ws[256 * WSS];   // 18,432 B: one W k-slice
  const int tid = threadIdx.x;
  const int v0 = blockIdx.x * 32;
  const int wave = tid >> 6, lane = tid & 63;
  const int l16 = lane & 15, quad = lane >> 4;
  const int rt = wave & 1;
  const int si = tid >> 3, sj = tid & 7;

  // ---- stage x | msg ----
  {
    const u16* xp = xb + ((size_t)(v0 + si) << 7) + sj * 16;
    *(u16x8*)&A1[si * A1S + sj * 16]     = *(const u16x8*)xp;
    *(u16x8*)&A1[si * A1S + sj * 16 + 8] = *(const u16x8*)(xp + 8);
    const u16* mp = msgb + ((size_t)(v0 + si) << 7) + sj * 16;
    *(u16x8*)&A1[si * A1S + 128 + sj * 16]     = *(const u16x8*)mp;
    *(u16x8*)&A1[si * A1S + 128 + sj * 16 + 8] = *(const u16x8*)(mp + 8);
  }

  // ---- phase B: mid = tanh([x | msg] @ W1 + b1) ----
  const int ch = (wave >> 1) << 7;
  f32x4 acc2[8] = {};
  for (int kt = 0; kt < 8; ++kt) {
    __syncthreads();   // kt=0: A1 staged; kt>0: prior Ws consumers done
    { // stage W1t[:, kt*32..+32]: thread tid covers output-row tid (64B)
      const u16* wp = W1t + (size_t)tid * 256 + kt * 32;
#pragma unroll
      for (int t = 0; t < 4; ++t)
        *(u16x8*)&Ws[tid * WSS + t * 8] = *(const u16x8*)(wp + t * 8);
    }
    __syncthreads();
    const bf16x8 af = *(const bf16x8*)&A1[(rt * 16 + l16) * A1S + kt * 32 + quad * 8];
#pragma unroll
    for (int ct = 0; ct < 8; ++ct) {
      const u16* wp = &Ws[(ch + ct * 16 + l16) * WSS + quad * 8];
      acc2[ct] = __builtin_amdgcn_mfma_f32_16x16x32_bf16(af, *(const bf16x8*)wp, acc2[ct], 0, 0, 0);
    }
  }
#pragma unroll
  for (int ct = 0; ct < 8; ++ct) {
    const int col = ch + ct * 16 + l16;
    const float bias = b1[col];
#pragma unroll
    for (int reg = 0; reg < 4; ++reg) {
      const int row = rt * 16 + quad * 4 + reg;
      Ht[row * A1S + col] = f2bf(tanhf(acc2[ct][reg] + bias));
    }
  }

  // ---- phase C: out = [x | mid] @ W2 + b2 ----
  const int cv = (wave >> 1) << 6;
  f32x4 acc3[4] = {};
  for (int kt = 0; kt < 12; ++kt) {
    __syncthreads();   // kt=0: Ht written; kt>0: prior Ws consumers done
    { // stage W2t[:, kt*32..+32]: 128 rows x 32 u16; thread covers 32B
      const int o = tid >> 1, cc = (tid & 1) * 16;
      const u16* wp = W2t + (size_t)o * 384 + kt * 32 + cc;
      *(u16x8*)&Ws[o * WSS + cc]     = *(const u16x8*)wp;
      *(u16x8*)&Ws[o * WSS + cc + 8] = *(const u16x8*)(wp + 8);
    }
    __syncthreads();
    bf16x8 af;
    if (kt < 4)
      af = *(const bf16x8*)&A1[(rt * 16 + l16) * A1S + kt * 32 + quad * 8];
    else
      af = *(const bf16x8*)&Ht[(rt * 16 + l16) * A1S + (kt - 4) * 32 + quad * 8];
#pragma unroll
    for (int ct = 0; ct < 4; ++ct) {
      const u16* wp = &Ws[(cv + ct * 16 + l16) * WSS + quad * 8];
      acc3[ct] = __builtin_amdgcn_mfma_f32_16x16x32_bf16(af, *(const bf16x8*)wp, acc3[ct], 0, 0, 0);
    }
  }
#pragma unroll
  for (int ct = 0; ct < 4; ++ct) {
    const int col = cv + ct * 16 + l16;
    const float bias = b2[col];
#pragma unroll
    for (int reg = 0; reg < 4; ++reg) {
      const int row = v0 + rt * 16 + quad * 4 + reg;
      out[(size_t)row * 128 + col] = acc3[ct][reg] + bias;
    }
  }
}

extern "C" void kernel_launch(void* const* d_in, const int* in_sizes, int n_in,
                              void* d_out, int out_size, void* d_ws, size_t ws_size,
                              hipStream_t stream) {
  (void)in_sizes; (void)n_in; (void)out_size; (void)ws_size;
  const float* x        = (const float*)d_in[0];
  const int*   src      = (const int*)d_in[1];
  const int*   dst      = (const int*)d_in[2];
  const int*   et       = (const int*)d_in[3];
  const float* W_rel    = (const float*)d_in[4];
  const float* loop_w   = (const float*)d_in[5];
  const float* rel_bias = (const float*)d_in[6];
  const float* W1       = (const float*)d_in[7];
  const float* b1       = (const float*)d_in[8];
  const float* W2       = (const float*)d_in[9];
  const float* b2       = (const float*)d_in[10];
  float* out = (float*)d_out;

  char* ws = (char*)d_ws;
  u16*      xb     = (u16*)(ws + OFF_XB);
  u16*      Wt     = (u16*)(ws + OFF_WT);
  u16*      W1t    = (u16*)(ws + OFF_W1T);
  u16*      W2t    = (u16*)(ws + OFF_W2T);
  unsigned* bucket = (unsigned*)(ws + OFF_BUCKET);
  int*      cur    = (int*)(ws + OFF_CUR);
  u16*      msgb   = (u16*)(ws + OFF_MSGB);

  hipMemsetAsync(cur, 0, (size_t)NT * 4, stream);

  // cvt sections (13524 blocks) + edge scatter (2500 blocks)
  k_cvt_all <<<16024, 256, 0, stream>>>(x, W_rel, loop_w, W1, W2, src, dst, et,
                                        xb, Wt, W1t, W2t, cur, bucket);

  k_msg     <<<NT, 256, 0, stream>>>(xb, Wt, cur, bucket, rel_bias, msgb);
  k_mlp     <<<NT, 256, 0, stream>>>(xb, msgb, W1t, b1, W2t, b2, out);
}

// Round 8
// 583.715 us; speedup vs baseline: 1.0745x; 1.0745x over previous
//
#include <hip/hip_runtime.h>

#define NN 100000   // nodes
#define NE 640000   // edges
#define RR 8        // relations
#define NT 3125     // 32-node tiles (NN/32)
#define CAP 512     // per-tile edge capacity (Poisson mean 205, +21 sigma)
// D = HID = OUT = 128 hard-coded below.

typedef unsigned short u16;
typedef u16 u16x4 __attribute__((ext_vector_type(4)));
typedef u16 u16x8 __attribute__((ext_vector_type(8)));
typedef __bf16 bf16x8 __attribute__((ext_vector_type(8)));
typedef float f32x4 __attribute__((ext_vector_type(4)));

// ---- workspace layout (bytes) ----
#define OFF_XB      0u          // bf16 N*128            = 25,600,000
#define OFF_WT      25600000u   // bf16 [9][128o][128d]  = 294,912 (8 rels + loop_w)
#define OFF_W1T     25894912u   // bf16 [256o][256i]     = 131,072
#define OFF_W2T     26025984u   // bf16 [128o][384i]     = 98,304
#define OFF_BUCKET  26124288u   // uint NT*CAP (packed src|rel<<17|dstlo<<20) = 6,400,000
#define OFF_CUR     32524288u   // int NT = 12,500

__device__ inline u16 f2bf(float f) {
  unsigned u = __float_as_uint(f);
  u += 0x7FFF + ((u >> 16) & 1);   // round-to-nearest-even
  return (u16)(u >> 16);
}
__device__ inline float bf2f(u16 h) { return __uint_as_float(((unsigned)h) << 16); }

// ---------------- prep: dtype cvt (x, W_rel+loop, W1, W2) + tile scatter ---
// grid: [0,12500) x | [12500,13076) wrel | [13076,13332) w1 |
//       [13332,13524) w2 | [13524,16024) edge scatter (640K edges)
// At ~90 MB of traffic this section runs AT the observed ~580 GB/s platform
// cap -- it is not improvable except by removing bytes (none removable).
__global__ void k_cvt_all(const float* __restrict__ x,
                          const float* __restrict__ W, const float* __restrict__ Lw,
                          const float* __restrict__ W1, const float* __restrict__ W2,
                          const int* __restrict__ src, const int* __restrict__ dst,
                          const int* __restrict__ et,
                          u16* __restrict__ xb, u16* __restrict__ Wt,
                          u16* __restrict__ W1t, u16* __restrict__ W2t,
                          int* __restrict__ cur, unsigned* __restrict__ bucket) {
  const int b = blockIdx.x, tid = threadIdx.x;
  if (b < 12500) {
    const int i = (b * 256 + tid) * 4;
    const float4 v = *(const float4*)(x + i);
    u16x4 o;
    o.x = f2bf(v.x); o.y = f2bf(v.y); o.z = f2bf(v.z); o.w = f2bf(v.w);
    *(u16x4*)(xb + i) = o;
  } else if (b < 13076) {          // 9*16384 = 147456 elems
    const int idx = (b - 12500) * 256 + tid;
    const int r = idx >> 14, o = (idx >> 7) & 127, d = idx & 127;
    Wt[idx] = f2bf(r < 8 ? W[(r << 14) + (d << 7) + o] : Lw[(d << 7) + o]);
  } else if (b < 13332) {          // 65536 elems
    const int idx = (b - 13076) * 256 + tid;
    const int o = idx >> 8, i = idx & 255;
    W1t[idx] = f2bf(W1[i * 256 + o]);
  } else if (b < 13524) {          // 49152 elems
    const int idx = (b - 13332) * 256 + tid;
    const int o = idx / 384, i = idx % 384;
    W2t[idx] = f2bf(W2[i * 128 + o]);
  } else {                         // edge scatter: append to per-tile bucket
    const int e = (b - 13524) * 256 + tid;   // grid sized exactly to NE
    const int d = dst[e], r = et[e];
    const int t = d >> 5;
    const int pos = atomicAdd(&cur[t], 1);
    if (pos < CAP)
      bucket[t * CAP + pos] =
          (unsigned)src[e] | ((unsigned)r << 17) | ((unsigned)(d & 31) << 20);
  }
}

// ---------------- fully fused per-32-node tile ----------------------------
// Best measured configuration (round 6, 584 us total / 430 us this kernel):
//   - in-LDS counting sort of the tile's <=512 edge words by (node,rel) bin
//   - 8 phases x 1 relation-tile gather+MFMA (2 node streams per 16-lane grp)
//   - phase B/C MLP fused behind the gather, msg/mid never touch HBM
// Session-wide finding: every phase runs at 65-100% of the platform's
// observed ~580 GB/s effective HBM cap; total bytes (~250 MB) set the floor.
#define ATS 136    // A-tile row stride (u16): 68 words, %32=4 -> 2-way (free)
__global__ __launch_bounds__(256, 5) void k_fused(
    const u16* __restrict__ xb, const u16* __restrict__ Wt,
    const int* __restrict__ cur, const unsigned* __restrict__ bucket,
    const float* __restrict__ rel_bias,
    const u16* __restrict__ W1t, const float* __restrict__ b1,
    const u16* __restrict__ W2t, const float* __restrict__ b2,
    float* __restrict__ out) {
  // union area: phase A uses first 8,704 B as the relation tile (32 x ATS);
  // phases B/C overlay Mt (32x136) + Ht (32x264) = 25,600 B total.
  // sort scratch (wraw/scnt/spos, 4 KB) overlays the Ht region (dead then).
  __shared__ u16 smem[32 * 136 + 32 * 264];   // 25,600 B
  __shared__ unsigned wlds[CAP];              //  2,048 B (sorted edge words)
  __shared__ int coff[257];                   //  1,028 B (tile-local bounds)
  const int tid = threadIdx.x;
  const int tile = blockIdx.x;
  const int v0 = tile * 32;
  const int wave = tid >> 6, lane = tid & 63;
  const int l16 = lane & 15, quad = lane >> 4;
  const int rt = wave & 1, cb = (wave >> 1) << 6;
  const int grp = tid >> 4, l16g = tid & 15;   // gather: 16 lanes per node

  u16* At = smem;                  // [32][ATS] single relation tile
  u16* Mt = smem;                  // [32][136] phase-B overlay
  u16* Ht = smem + 32 * 136;       // [32][264] phase-B/C overlay
  unsigned* wraw = (unsigned*)(smem + 4352);   // 2,048 B in Ht region
  int* scnt = (int*)(smem + 5376);             // 1,024 B
  int* spos = (int*)(smem + 5888);             // 1,024 B

  // ---- in-LDS counting sort by (node,rel) bin ----
  const int n_raw = cur[tile];
  const int n = n_raw < CAP ? n_raw : CAP;
  for (int i = tid; i < n; i += 256) wraw[i] = bucket[tile * CAP + i];
  scnt[tid] = 0;
  __syncthreads();
  for (int i = tid; i < n; i += 256)
    atomicAdd(&scnt[(wraw[i] >> 17) & 0xFF], 1);   // bin = dstlo*8 + rel
  __syncthreads();
  const int myc = scnt[tid];
  for (int d = 1; d < 256; d <<= 1) {               // Hillis-Steele inclusive
    const int t = (tid >= d) ? scnt[tid - d] : 0;
    __syncthreads();
    scnt[tid] += t;
    __syncthreads();
  }
  coff[tid] = scnt[tid] - myc;                      // exclusive
  spos[tid] = scnt[tid] - myc;
  if (tid == 0) coff[256] = n;
  __syncthreads();
  for (int i = tid; i < n; i += 256) {
    const unsigned w = wraw[i];
    const int pos = atomicAdd(&spos[(w >> 17) & 0xFF], 1);
    wlds[pos] = w;
  }

  f32x4 acc[4] = {};

  // ---- self-loop: A-frags straight from global xb ----
  {
    const u16* xp = xb + ((size_t)(v0 + rt * 16 + l16) << 7) + quad * 8;
    bf16x8 afr[4];
#pragma unroll
    for (int t = 0; t < 4; ++t) afr[t] = *(const bf16x8*)(xp + t * 32);
    const u16* wb = Wt + (8 << 14);
#pragma unroll
    for (int c = 0; c < 4; ++c) {
      const u16* wp = wb + (size_t)(cb + c * 16 + l16) * 128 + quad * 8;
#pragma unroll
      for (int t = 0; t < 4; ++t)
        acc[c] = __builtin_amdgcn_mfma_f32_16x16x32_bf16(afr[t], *(const bf16x8*)(wp + t * 32), acc[c], 0, 0, 0);
    }
  }
  __syncthreads();

  for (int ph = 0; ph < 8; ++ph) {
    // ---- gather+accumulate: 2 independent node streams per 16-lane group --
    {
      const int nodeA = grp, nodeB = grp + 16;
      const int begA = coff[nodeA * 8 + ph];
      const int nA   = coff[nodeA * 8 + ph + 1] - begA;
      const int begB = coff[nodeB * 8 + ph];
      const int nB   = coff[nodeB * 8 + ph + 1] - begB;
      float a0[8] = {}, a1[8] = {};
      const int nmax = nA > nB ? nA : nB;
      for (int j = 0; j < nmax; ++j) {
        const bool dA = j < nA, dB = j < nB;
        unsigned wA = 0, wB = 0;
        if (dA) wA = wlds[begA + j];
        if (dB) wB = wlds[begB + j];
        u16x8 hA, hB;
        if (dA) hA = *(const u16x8*)(xb + ((size_t)(wA & 0x1FFFFu) << 7) + l16g * 8);
        if (dB) hB = *(const u16x8*)(xb + ((size_t)(wB & 0x1FFFFu) << 7) + l16g * 8);
        if (dA) {
#pragma unroll
          for (int u = 0; u < 8; ++u) a0[u] += bf2f(hA[u]);
        }
        if (dB) {
#pragma unroll
          for (int u = 0; u < 8; ++u) a1[u] += bf2f(hB[u]);
        }
      }
      // unconditional tile write (zero accumulator == zero contribution)
      u16x8 o0, o1;
#pragma unroll
      for (int u = 0; u < 8; ++u) { o0[u] = f2bf(a0[u]); o1[u] = f2bf(a1[u]); }
      *(u16x8*)&At[nodeA * ATS + l16g * 8] = o0;
      *(u16x8*)&At[nodeB * ATS + l16g * 8] = o1;
    }
    __syncthreads();

    // ---- MFMA over this relation's tile ----
    {
      bf16x8 afr[4];
#pragma unroll
      for (int t = 0; t < 4; ++t)
        afr[t] = *(const bf16x8*)&At[(rt * 16 + l16) * ATS + quad * 8 + t * 32];
      const u16* wb = Wt + (ph << 14);
#pragma unroll
      for (int c = 0; c < 4; ++c) {
        const u16* wp = wb + (size_t)(cb + c * 16 + l16) * 128 + quad * 8;
#pragma unroll
        for (int t = 0; t < 4; ++t)
          acc[c] = __builtin_amdgcn_mfma_f32_16x16x32_bf16(afr[t], *(const bf16x8*)(wp + t * 32), acc[c], 0, 0, 0);
      }
    }
    __syncthreads();
  }

  // ---- phase A epilogue: msg = acc + rel_bias -> bf16 LDS tile (no HBM) --
#pragma unroll
  for (int c = 0; c < 4; ++c) {
    const int col = cb + c * 16 + l16;
    const float bias = rel_bias[col];
#pragma unroll
    for (int reg = 0; reg < 4; ++reg) {
      const int row = rt * 16 + quad * 4 + reg;
      Mt[row * 136 + col] = f2bf(acc[c][reg] + bias);
    }
  }
  __syncthreads();

  // ---- phase B: mid = tanh([x | msg] @ W1 + b1) -> bf16 LDS tile ---------
  {
    const int ch = (wave >> 1) << 7;
    f32x4 acc2[8] = {};
#pragma unroll
    for (int kt = 0; kt < 8; ++kt) {
      bf16x8 af;
      if (kt < 4)
        af = *(const bf16x8*)(xb + ((size_t)(v0 + rt * 16 + l16) << 7) + kt * 32 + quad * 8);
      else
        af = *(const bf16x8*)&Mt[(rt * 16 + l16) * 136 + (kt - 4) * 32 + quad * 8];
#pragma unroll
      for (int ct = 0; ct < 8; ++ct) {
        const u16* wp = W1t + (size_t)(ch + ct * 16 + l16) * 256 + kt * 32 + quad * 8;
        acc2[ct] = __builtin_amdgcn_mfma_f32_16x16x32_bf16(af, *(const bf16x8*)(wp), acc2[ct], 0, 0, 0);
      }
    }
    __syncthreads();   // Mt reads must finish before Ht writes (overlay-safe)
#pragma unroll
    for (int ct = 0; ct < 8; ++ct) {
      const int col = ch + ct * 16 + l16;
      const float bias = b1[col];
#pragma unroll
      for (int reg = 0; reg < 4; ++reg) {
        const int row = rt * 16 + quad * 4 + reg;
        Ht[row * 264 + col] = f2bf(tanhf(acc2[ct][reg] + bias));
      }
    }
  }
  __syncthreads();

  // ---- phase C: out = [x | mid] @ W2 + b2 -> global ----------------------
  {
    f32x4 acc3[4] = {};
#pragma unroll
    for (int kt = 0; kt < 12; ++kt) {
      bf16x8 af;
      if (kt < 4)
        af = *(const bf16x8*)(xb + ((size_t)(v0 + rt * 16 + l16) << 7) + kt * 32 + quad * 8);
      else
        af = *(const bf16x8*)&Ht[(rt * 16 + l16) * 264 + (kt - 4) * 32 + quad * 8];
#pragma unroll
      for (int ct = 0; ct < 4; ++ct) {
        const u16* wp = W2t + (size_t)(cb + ct * 16 + l16) * 384 + kt * 32 + quad * 8;
        acc3[ct] = __builtin_amdgcn_mfma_f32_16x16x32_bf16(af, *(const bf16x8*)(wp), acc3[ct], 0, 0, 0);
      }
    }
#pragma unroll
    for (int ct = 0; ct < 4; ++ct) {
      const int col = cb + ct * 16 + l16;
      const float bias = b2[col];
#pragma unroll
      for (int reg = 0; reg < 4; ++reg) {
        const int row = v0 + rt * 16 + quad * 4 + reg;
        out[(size_t)row * 128 + col] = acc3[ct][reg] + bias;
      }
    }
  }
}

extern "C" void kernel_launch(void* const* d_in, const int* in_sizes, int n_in,
                              void* d_out, int out_size, void* d_ws, size_t ws_size,
                              hipStream_t stream) {
  (void)in_sizes; (void)n_in; (void)out_size; (void)ws_size;
  const float* x        = (const float*)d_in[0];
  const int*   src      = (const int*)d_in[1];
  const int*   dst      = (const int*)d_in[2];
  const int*   et       = (const int*)d_in[3];
  const float* W_rel    = (const float*)d_in[4];
  const float* loop_w   = (const float*)d_in[5];
  const float* rel_bias = (const float*)d_in[6];
  const float* W1       = (const float*)d_in[7];
  const float* b1       = (const float*)d_in[8];
  const float* W2       = (const float*)d_in[9];
  const float* b2       = (const float*)d_in[10];
  float* out = (float*)d_out;

  char* ws = (char*)d_ws;
  u16*      xb     = (u16*)(ws + OFF_XB);
  u16*      Wt     = (u16*)(ws + OFF_WT);
  u16*      W1t    = (u16*)(ws + OFF_W1T);
  u16*      W2t    = (u16*)(ws + OFF_W2T);
  unsigned* bucket = (unsigned*)(ws + OFF_BUCKET);
  int*      cur    = (int*)(ws + OFF_CUR);

  hipMemsetAsync(cur, 0, (size_t)NT * 4, stream);

  // cvt sections (13524 blocks) + edge scatter (2500 blocks)
  k_cvt_all <<<16024, 256, 0, stream>>>(x, W_rel, loop_w, W1, W2, src, dst, et,
                                        xb, Wt, W1t, W2t, cur, bucket);

  k_fused   <<<NT, 256, 0, stream>>>(xb, Wt, cur, bucket, rel_bias,
                                     W1t, b1, W2t, b2, out);
}

// Round 9
// 578.514 us; speedup vs baseline: 1.0842x; 1.0090x over previous
//
#include <hip/hip_runtime.h>

#define NN 100000   // nodes
#define NE 640000   // edges
#define RR 8        // relations
#define NT 3125     // 32-node tiles (NN/32)
#define CAP 512     // per-tile edge capacity (Poisson mean 205, +21 sigma)
// D = HID = OUT = 128 hard-coded below.

typedef unsigned short u16;
typedef u16 u16x4 __attribute__((ext_vector_type(4)));
typedef u16 u16x8 __attribute__((ext_vector_type(8)));
typedef __bf16 bf16x8 __attribute__((ext_vector_type(8)));
typedef float f32x4 __attribute__((ext_vector_type(4)));

// ---- workspace layout (bytes) ----
#define OFF_XB      0u          // bf16 N*128            = 25,600,000
#define OFF_WT      25600000u   // bf16 [9][128o][128d]  = 294,912 (8 rels + loop_w)
#define OFF_W1T     25894912u   // bf16 [256o][256i]     = 131,072
#define OFF_W2T     26025984u   // bf16 [128o][384i]     = 98,304
#define OFF_BUCKET  26124288u   // uint NT*CAP (packed src|rel<<17|dstlo<<20) = 6,400,000
#define OFF_CUR     32524288u   // int NT = 12,500

__device__ inline u16 f2bf(float f) {
  unsigned u = __float_as_uint(f);
  u += 0x7FFF + ((u >> 16) & 1);   // round-to-nearest-even
  return (u16)(u >> 16);
}
__device__ inline float bf2f(u16 h) { return __uint_as_float(((unsigned)h) << 16); }

// asm 16B load: volatile ordering guarantees issue-before-waitcnt; the
// compiler CANNOT sink this to its use (the round-1/2 failure mode).
__device__ __forceinline__ u16x8 gload16(const u16* ap) {
  u16x8 d;
  asm volatile("global_load_dwordx4 %0, %1, off" : "=v"(d) : "v"(ap));
  return d;
}
__device__ __forceinline__ void acc8(float* a, const u16x8 h) {
#pragma unroll
  for (int u = 0; u < 8; ++u) a[u] += bf2f(h[u]);
}

// ---------------- prep: dtype cvt (x, W_rel+loop, W1, W2) + tile scatter ---
// grid: [0,12500) x | [12500,13076) wrel | [13076,13332) w1 |
//       [13332,13524) w2 | [13524,16024) edge scatter (640K edges)
__global__ void k_cvt_all(const float* __restrict__ x,
                          const float* __restrict__ W, const float* __restrict__ Lw,
                          const float* __restrict__ W1, const float* __restrict__ W2,
                          const int* __restrict__ src, const int* __restrict__ dst,
                          const int* __restrict__ et,
                          u16* __restrict__ xb, u16* __restrict__ Wt,
                          u16* __restrict__ W1t, u16* __restrict__ W2t,
                          int* __restrict__ cur, unsigned* __restrict__ bucket) {
  const int b = blockIdx.x, tid = threadIdx.x;
  if (b < 12500) {
    const int i = (b * 256 + tid) * 4;
    const float4 v = *(const float4*)(x + i);
    u16x4 o;
    o.x = f2bf(v.x); o.y = f2bf(v.y); o.z = f2bf(v.z); o.w = f2bf(v.w);
    *(u16x4*)(xb + i) = o;
  } else if (b < 13076) {          // 9*16384 = 147456 elems
    const int idx = (b - 12500) * 256 + tid;
    const int r = idx >> 14, o = (idx >> 7) & 127, d = idx & 127;
    Wt[idx] = f2bf(r < 8 ? W[(r << 14) + (d << 7) + o] : Lw[(d << 7) + o]);
  } else if (b < 13332) {          // 65536 elems
    const int idx = (b - 13076) * 256 + tid;
    const int o = idx >> 8, i = idx & 255;
    W1t[idx] = f2bf(W1[i * 256 + o]);
  } else if (b < 13524) {          // 49152 elems
    const int idx = (b - 13332) * 256 + tid;
    const int o = idx / 384, i = idx % 384;
    W2t[idx] = f2bf(W2[i * 128 + o]);
  } else {                         // edge scatter: append to per-tile bucket
    const int e = (b - 13524) * 256 + tid;   // grid sized exactly to NE
    const int d = dst[e], r = et[e];
    const int t = d >> 5;
    const int pos = atomicAdd(&cur[t], 1);
    if (pos < CAP)
      bucket[t * CAP + pos] =
          (unsigned)src[e] | ((unsigned)r << 17) | ((unsigned)(d & 31) << 20);
  }
}

// ---------------- fully fused per-32-node tile ----------------------------
// r6 structure (best measured) + THIS ROUND: asm-batched gather.  Per phase
// per 16-lane group, up to 4+4 guarded global_load_dwordx4 are issued
// back-to-back (volatile order), ONE s_waitcnt vmcnt(0) + sched_barrier(0),
// then accumulate.  A bin's serial chain of k edges costs ceil(k/4) memory
// round-trips instead of k -- attacks the barrier-coupled tail that the
// cycle model says is ~60% of this kernel's time.
#define ATS 136    // A-tile row stride (u16): 68 words, %32=4 -> 2-way (free)
__global__ __launch_bounds__(256, 5) void k_fused(
    const u16* __restrict__ xb, const u16* __restrict__ Wt,
    const int* __restrict__ cur, const unsigned* __restrict__ bucket,
    const float* __restrict__ rel_bias,
    const u16* __restrict__ W1t, const float* __restrict__ b1,
    const u16* __restrict__ W2t, const float* __restrict__ b2,
    float* __restrict__ out) {
  // union area: phase A uses first 8,704 B as the relation tile (32 x ATS);
  // phases B/C overlay Mt (32x136) + Ht (32x264) = 25,600 B total.
  // sort scratch (wraw/scnt/spos, 4 KB) overlays the Ht region (dead then).
  __shared__ u16 smem[32 * 136 + 32 * 264];   // 25,600 B
  __shared__ unsigned wlds[CAP];              //  2,048 B (sorted edge words)
  __shared__ int coff[257];                   //  1,028 B (tile-local bounds)
  const int tid = threadIdx.x;
  const int tile = blockIdx.x;
  const int v0 = tile * 32;
  const int wave = tid >> 6, lane = tid & 63;
  const int l16 = lane & 15, quad = lane >> 4;
  const int rt = wave & 1, cb = (wave >> 1) << 6;
  const int grp = tid >> 4, l16g = tid & 15;   // gather: 16 lanes per node

  u16* At = smem;                  // [32][ATS] single relation tile
  u16* Mt = smem;                  // [32][136] phase-B overlay
  u16* Ht = smem + 32 * 136;       // [32][264] phase-B/C overlay
  unsigned* wraw = (unsigned*)(smem + 4352);   // 2,048 B in Ht region
  int* scnt = (int*)(smem + 5376);             // 1,024 B
  int* spos = (int*)(smem + 5888);             // 1,024 B

  // ---- in-LDS counting sort by (node,rel) bin ----
  const int n_raw = cur[tile];
  const int n = n_raw < CAP ? n_raw : CAP;
  for (int i = tid; i < n; i += 256) wraw[i] = bucket[tile * CAP + i];
  scnt[tid] = 0;
  __syncthreads();
  for (int i = tid; i < n; i += 256)
    atomicAdd(&scnt[(wraw[i] >> 17) & 0xFF], 1);   // bin = dstlo*8 + rel
  __syncthreads();
  const int myc = scnt[tid];
  for (int d = 1; d < 256; d <<= 1) {               // Hillis-Steele inclusive
    const int t = (tid >= d) ? scnt[tid - d] : 0;
    __syncthreads();
    scnt[tid] += t;
    __syncthreads();
  }
  coff[tid] = scnt[tid] - myc;                      // exclusive
  spos[tid] = scnt[tid] - myc;
  if (tid == 0) coff[256] = n;
  __syncthreads();
  for (int i = tid; i < n; i += 256) {
    const unsigned w = wraw[i];
    const int pos = atomicAdd(&spos[(w >> 17) & 0xFF], 1);
    wlds[pos] = w;
  }

  f32x4 acc[4] = {};

  // ---- self-loop: A-frags straight from global xb ----
  {
    const u16* xp = xb + ((size_t)(v0 + rt * 16 + l16) << 7) + quad * 8;
    bf16x8 afr[4];
#pragma unroll
    for (int t = 0; t < 4; ++t) afr[t] = *(const bf16x8*)(xp + t * 32);
    const u16* wb = Wt + (8 << 14);
#pragma unroll
    for (int c = 0; c < 4; ++c) {
      const u16* wp = wb + (size_t)(cb + c * 16 + l16) * 128 + quad * 8;
#pragma unroll
      for (int t = 0; t < 4; ++t)
        acc[c] = __builtin_amdgcn_mfma_f32_16x16x32_bf16(afr[t], *(const bf16x8*)(wp + t * 32), acc[c], 0, 0, 0);
    }
  }
  __syncthreads();

  for (int ph = 0; ph < 8; ++ph) {
    // ---- gather+accumulate: asm-batched, 2 node streams per 16-lane group -
    {
      const int nodeA = grp, nodeB = grp + 16;
      const int begA = coff[nodeA * 8 + ph];
      const int nA   = coff[nodeA * 8 + ph + 1] - begA;
      const int begB = coff[nodeB * 8 + ph];
      const int nB   = coff[nodeB * 8 + ph + 1] - begB;
      float a0[8] = {}, a1[8] = {};
      const int nmax = nA > nB ? nA : nB;
      for (int jb = 0; jb < nmax; jb += 4) {
        u16x8 hA0, hA1, hA2, hA3, hB0, hB1, hB2, hB3;
        // issue phase: up to 8 loads in flight (volatile order preserved)
        if (jb + 0 < nA) hA0 = gload16(xb + ((size_t)(wlds[begA + jb + 0] & 0x1FFFFu) << 7) + l16g * 8);
        if (jb + 0 < nB) hB0 = gload16(xb + ((size_t)(wlds[begB + jb + 0] & 0x1FFFFu) << 7) + l16g * 8);
        if (jb + 1 < nA) hA1 = gload16(xb + ((size_t)(wlds[begA + jb + 1] & 0x1FFFFu) << 7) + l16g * 8);
        if (jb + 1 < nB) hB1 = gload16(xb + ((size_t)(wlds[begB + jb + 1] & 0x1FFFFu) << 7) + l16g * 8);
        if (jb + 2 < nA) hA2 = gload16(xb + ((size_t)(wlds[begA + jb + 2] & 0x1FFFFu) << 7) + l16g * 8);
        if (jb + 2 < nB) hB2 = gload16(xb + ((size_t)(wlds[begB + jb + 2] & 0x1FFFFu) << 7) + l16g * 8);
        if (jb + 3 < nA) hA3 = gload16(xb + ((size_t)(wlds[begA + jb + 3] & 0x1FFFFu) << 7) + l16g * 8);
        if (jb + 3 < nB) hB3 = gload16(xb + ((size_t)(wlds[begB + jb + 3] & 0x1FFFFu) << 7) + l16g * 8);
        // single drain + hard scheduling fence (rule #18)
        asm volatile("s_waitcnt vmcnt(0)" ::: "memory");
        __builtin_amdgcn_sched_barrier(0);
        // consume phase (guards mirror the issue guards exactly)
        if (jb + 0 < nA) acc8(a0, hA0);
        if (jb + 1 < nA) acc8(a0, hA1);
        if (jb + 2 < nA) acc8(a0, hA2);
        if (jb + 3 < nA) acc8(a0, hA3);
        if (jb + 0 < nB) acc8(a1, hB0);
        if (jb + 1 < nB) acc8(a1, hB1);
        if (jb + 2 < nB) acc8(a1, hB2);
        if (jb + 3 < nB) acc8(a1, hB3);
      }
      // unconditional tile write (zero accumulator == zero contribution)
      u16x8 o0, o1;
#pragma unroll
      for (int u = 0; u < 8; ++u) { o0[u] = f2bf(a0[u]); o1[u] = f2bf(a1[u]); }
      *(u16x8*)&At[nodeA * ATS + l16g * 8] = o0;
      *(u16x8*)&At[nodeB * ATS + l16g * 8] = o1;
    }
    __syncthreads();

    // ---- MFMA over this relation's tile ----
    {
      bf16x8 afr[4];
#pragma unroll
      for (int t = 0; t < 4; ++t)
        afr[t] = *(const bf16x8*)&At[(rt * 16 + l16) * ATS + quad * 8 + t * 32];
      const u16* wb = Wt + (ph << 14);
#pragma unroll
      for (int c = 0; c < 4; ++c) {
        const u16* wp = wb + (size_t)(cb + c * 16 + l16) * 128 + quad * 8;
#pragma unroll
        for (int t = 0; t < 4; ++t)
          acc[c] = __builtin_amdgcn_mfma_f32_16x16x32_bf16(afr[t], *(const bf16x8*)(wp + t * 32), acc[c], 0, 0, 0);
      }
    }
    __syncthreads();
  }

  // ---- phase A epilogue: msg = acc + rel_bias -> bf16 LDS tile (no HBM) --
#pragma unroll
  for (int c = 0; c < 4; ++c) {
    const int col = cb + c * 16 + l16;
    const float bias = rel_bias[col];
#pragma unroll
    for (int reg = 0; reg < 4; ++reg) {
      const int row = rt * 16 + quad * 4 + reg;
      Mt[row * 136 + col] = f2bf(acc[c][reg] + bias);
    }
  }
  __syncthreads();

  // ---- phase B: mid = tanh([x | msg] @ W1 + b1) -> bf16 LDS tile ---------
  {
    const int ch = (wave >> 1) << 7;
    f32x4 acc2[8] = {};
#pragma unroll
    for (int kt = 0; kt < 8; ++kt) {
      bf16x8 af;
      if (kt < 4)
        af = *(const bf16x8*)(xb + ((size_t)(v0 + rt * 16 + l16) << 7) + kt * 32 + quad * 8);
      else
        af = *(const bf16x8*)&Mt[(rt * 16 + l16) * 136 + (kt - 4) * 32 + quad * 8];
#pragma unroll
      for (int ct = 0; ct < 8; ++ct) {
        const u16* wp = W1t + (size_t)(ch + ct * 16 + l16) * 256 + kt * 32 + quad * 8;
        acc2[ct] = __builtin_amdgcn_mfma_f32_16x16x32_bf16(af, *(const bf16x8*)(wp), acc2[ct], 0, 0, 0);
      }
    }
    __syncthreads();   // Mt reads must finish before Ht writes (overlay-safe)
#pragma unroll
    for (int ct = 0; ct < 8; ++ct) {
      const int col = ch + ct * 16 + l16;
      const float bias = b1[col];
#pragma unroll
      for (int reg = 0; reg < 4; ++reg) {
        const int row = rt * 16 + quad * 4 + reg;
        Ht[row * 264 + col] = f2bf(tanhf(acc2[ct][reg] + bias));
      }
    }
  }
  __syncthreads();

  // ---- phase C: out = [x | mid] @ W2 + b2 -> global ----------------------
  {
    f32x4 acc3[4] = {};
#pragma unroll
    for (int kt = 0; kt < 12; ++kt) {
      bf16x8 af;
      if (kt < 4)
        af = *(const bf16x8*)(xb + ((size_t)(v0 + rt * 16 + l16) << 7) + kt * 32 + quad * 8);
      else
        af = *(const bf16x8*)&Ht[(rt * 16 + l16) * 264 + (kt - 4) * 32 + quad * 8];
#pragma unroll
      for (int ct = 0; ct < 4; ++ct) {
        const u16* wp = W2t + (size_t)(cb + ct * 16 + l16) * 384 + kt * 32 + quad * 8;
        acc3[ct] = __builtin_amdgcn_mfma_f32_16x16x32_bf16(af, *(const bf16x8*)(wp), acc3[ct], 0, 0, 0);
      }
    }
#pragma unroll
    for (int ct = 0; ct < 4; ++ct) {
      const int col = cb + ct * 16 + l16;
      const float bias = b2[col];
#pragma unroll
      for (int reg = 0; reg < 4; ++reg) {
        const int row = v0 + rt * 16 + quad * 4 + reg;
        out[(size_t)row * 128 + col] = acc3[ct][reg] + bias;
      }
    }
  }
}

extern "C" void kernel_launch(void* const* d_in, const int* in_sizes, int n_in,
                              void* d_out, int out_size, void* d_ws, size_t ws_size,
                              hipStream_t stream) {
  (void)in_sizes; (void)n_in; (void)out_size; (void)ws_size;
  const float* x        = (const float*)d_in[0];
  const int*   src      = (const int*)d_in[1];
  const int*   dst      = (const int*)d_in[2];
  const int*   et       = (const int*)d_in[3];
  const float* W_rel    = (const float*)d_in[4];
  const float* loop_w   = (const float*)d_in[5];
  const float* rel_bias = (const float*)d_in[6];
  const float* W1       = (const float*)d_in[7];
  const float* b1       = (const float*)d_in[8];
  const float* W2       = (const float*)d_in[9];
  const float* b2       = (const float*)d_in[10];
  float* out = (float*)d_out;

  char* ws = (char*)d_ws;
  u16*      xb     = (u16*)(ws + OFF_XB);
  u16*      Wt     = (u16*)(ws + OFF_WT);
  u16*      W1t    = (u16*)(ws + OFF_W1T);
  u16*      W2t    = (u16*)(ws + OFF_W2T);
  unsigned* bucket = (unsigned*)(ws + OFF_BUCKET);
  int*      cur    = (int*)(ws + OFF_CUR);

  hipMemsetAsync(cur, 0, (size_t)NT * 4, stream);

  // cvt sections (13524 blocks) + edge scatter (2500 blocks)
  k_cvt_all <<<16024, 256, 0, stream>>>(x, W_rel, loop_w, W1, W2, src, dst, et,
                                        xb, Wt, W1t, W2t, cur, bucket);

  k_fused   <<<NT, 256, 0, stream>>>(xb, Wt, cur, bucket, rel_bias,
                                     W1t, b1, W2t, b2, out);
}